// Round 1
// baseline (628.941 us; speedup 1.0000x reference)
//
#include <hip/hip_runtime.h>
#include <math.h>

// Problem constants (fixed by reference)
#define S   8000     // L = 20*20*20
#define BB  2
#define CC  96
#define DI  192      // d_inner
#define NS  16       // d_state
#define RK  6        // dt_rank
#define GG  6        // B * 3 directions
#define NC  25       // scan chunks
#define LC  320      // chunk length
#define ND  38       // dt_rank + 2*d_state

// l -> pos mapping per direction.
// dir0: l = d*400+h*20+w  (identity)
// dir1: l = h*400+w*20+d
// dir2: l = w*400+d*20+h
__device__ __forceinline__ int pos_from_l(int dir, int l) {
  if (dir == 0) return l;
  int a  = l / 400;
  int r  = l - a * 400;
  int bq = r / 20;
  int cq = r - bq * 20;
  if (dir == 1) return cq * 400 + a * 20 + bq;   // (h=a, w=bq, d=cq)
  return bq * 400 + cq * 20 + a;                 // (w=a, d=bq, h=cq)
}

// 16-lane butterfly sum via DPP (all lanes end with the group sum)
__device__ __forceinline__ float red16(float x) {
  x += __int_as_float(__builtin_amdgcn_update_dpp(0, __float_as_int(x), 0xB1, 0xF, 0xF, true));  // quad_perm [1,0,3,2]
  x += __int_as_float(__builtin_amdgcn_update_dpp(0, __float_as_int(x), 0x4E, 0xF, 0xF, true));  // quad_perm [2,3,0,1]
  x += __int_as_float(__builtin_amdgcn_update_dpp(0, __float_as_int(x), 0x141, 0xF, 0xF, true)); // row_half_mirror
  x += __int_as_float(__builtin_amdgcn_update_dpp(0, __float_as_int(x), 0x140, 0xF, 0xF, true)); // row_mirror
  return x;
}

// ---------------- K0: double LayerNorm over channels (per position) -------
__global__ __launch_bounds__(256) void k_ln2(const float* __restrict__ x,
    const float* __restrict__ lnw, const float* __restrict__ lnb,
    const float* __restrict__ mlnw, const float* __restrict__ mlnb,
    float* __restrict__ xn) {
  int t = blockIdx.x * blockDim.x + threadIdx.x;
  if (t >= BB * S) return;
  int b = t / S, pos = t - b * S;
  const float* xp = x + (size_t)b * CC * S + pos;
  float s1 = 0.f, s2 = 0.f;
  for (int c = 0; c < CC; ++c) { float v = xp[(size_t)c * S]; s1 += v; s2 += v * v; }
  float u = s1 * (1.f / CC);
  float var = s2 * (1.f / CC) - u * u;
  float rstd = rsqrtf(var + 1e-6f);
  float t1 = 0.f, t2 = 0.f;
  for (int c = 0; c < CC; ++c) {
    float y1 = fmaf(lnw[c], (xp[(size_t)c * S] - u) * rstd, lnb[c]);
    t1 += y1; t2 += y1 * y1;
  }
  float u2 = t1 * (1.f / CC);
  float var2 = t2 * (1.f / CC) - u2 * u2;
  float rstd2 = rsqrtf(var2 + 1e-5f);
  float* o = xn + (size_t)t * CC;
  for (int c = 0; c < CC; ++c) {
    float y1 = fmaf(lnw[c], (xp[(size_t)c * S] - u) * rstd, lnb[c]);
    o[c] = fmaf(mlnw[c], (y1 - u2) * rstd2, mlnb[c]);
  }
}

// ---------------- K8a: single LayerNorm (B,C,S) -> (B*S,C) ---------------
__global__ __launch_bounds__(256) void k_ln1(const float* __restrict__ xi,
    const float* __restrict__ lnw, const float* __restrict__ lnb,
    float* __restrict__ out) {
  int t = blockIdx.x * blockDim.x + threadIdx.x;
  if (t >= BB * S) return;
  int b = t / S, pos = t - b * S;
  const float* xp = xi + (size_t)b * CC * S + pos;
  float s1 = 0.f, s2 = 0.f;
  for (int c = 0; c < CC; ++c) { float v = xp[(size_t)c * S]; s1 += v; s2 += v * v; }
  float u = s1 * (1.f / CC);
  float var = s2 * (1.f / CC) - u * u;
  float rstd = rsqrtf(var + 1e-6f);
  float* o = out + (size_t)t * CC;
  for (int c = 0; c < CC; ++c)
    o[c] = fmaf(lnw[c], (xp[(size_t)c * S] - u) * rstd, lnb[c]);
}

// ---------------- generic fp32 GEMM: C = act(A[M,K] @ Bw[N,K]^T + bias) ---
// ACT: 0 none, 1 exact gelu. RESID/OUT_BCS use (B,CC,S) layout (N must be CC).
template <int ACT, bool BIAS, bool RESID, bool OUT_BCS>
__global__ __launch_bounds__(256) void k_gemm(const float* __restrict__ A,
    const float* __restrict__ Bw, const float* __restrict__ bias,
    const float* __restrict__ resid, float* __restrict__ Cmat,
    int M, int N, int K) {
  __shared__ float As[16][68];
  __shared__ float Bs[16][68];
  int tid = threadIdx.x;
  int tx = tid & 15, ty = tid >> 4;
  int m0 = blockIdx.x * 64, n0 = blockIdx.y * 64;
  float acc[4][4] = {};
  for (int kk = 0; kk < K; kk += 16) {
#pragma unroll
    for (int i = 0; i < 4; ++i) {
      int idx = tid + i * 256;
      int am = idx >> 4, ak = idx & 15;
      As[ak][am] = A[(size_t)(m0 + am) * K + kk + ak];      // M assumed %64==0
    }
#pragma unroll
    for (int i = 0; i < 4; ++i) {
      int idx = tid + i * 256;
      int bn = idx >> 4, bk = idx & 15;
      Bs[bk][bn] = (n0 + bn < N) ? Bw[(size_t)(n0 + bn) * K + kk + bk] : 0.f;
    }
    __syncthreads();
#pragma unroll
    for (int k = 0; k < 16; ++k) {
      float4 av = *(const float4*)&As[k][ty * 4];
      float4 bv = *(const float4*)&Bs[k][tx * 4];
      acc[0][0] = fmaf(av.x, bv.x, acc[0][0]);
      acc[0][1] = fmaf(av.x, bv.y, acc[0][1]);
      acc[0][2] = fmaf(av.x, bv.z, acc[0][2]);
      acc[0][3] = fmaf(av.x, bv.w, acc[0][3]);
      acc[1][0] = fmaf(av.y, bv.x, acc[1][0]);
      acc[1][1] = fmaf(av.y, bv.y, acc[1][1]);
      acc[1][2] = fmaf(av.y, bv.z, acc[1][2]);
      acc[1][3] = fmaf(av.y, bv.w, acc[1][3]);
      acc[2][0] = fmaf(av.z, bv.x, acc[2][0]);
      acc[2][1] = fmaf(av.z, bv.y, acc[2][1]);
      acc[2][2] = fmaf(av.z, bv.z, acc[2][2]);
      acc[2][3] = fmaf(av.z, bv.w, acc[2][3]);
      acc[3][0] = fmaf(av.w, bv.x, acc[3][0]);
      acc[3][1] = fmaf(av.w, bv.y, acc[3][1]);
      acc[3][2] = fmaf(av.w, bv.z, acc[3][2]);
      acc[3][3] = fmaf(av.w, bv.w, acc[3][3]);
    }
    __syncthreads();
  }
#pragma unroll
  for (int i = 0; i < 4; ++i) {
    int m = m0 + ty * 4 + i;
#pragma unroll
    for (int j = 0; j < 4; ++j) {
      int n = n0 + tx * 4 + j;
      if (n < N) {
        float v = acc[i][j];
        if (BIAS) v += bias[n];
        if (ACT == 1) v = 0.5f * v * (1.f + erff(v * 0.70710678118654752f));
        if (RESID || OUT_BCS) {
          int bb = m / S, pp = m - bb * S;
          size_t oidx = ((size_t)bb * CC + n) * S + pp;
          if (RESID) v += resid[oidx];
          if (OUT_BCS) { Cmat[oidx] = v; continue; }
        }
        Cmat[(size_t)m * N + n] = v;
      }
    }
  }
}

// ---------------- K2: causal depthwise conv(4) + SiLU, gathered input ----
__global__ __launch_bounds__(256) void k_conv(const float* __restrict__ XZ,
    const float* __restrict__ cw, const float* __restrict__ cb,
    float* __restrict__ xc) {
  int t = blockIdx.x * blockDim.x + threadIdx.x;
  if (t >= GG * S * DI) return;
  int e = t % DI; int gl = t / DI; int l = gl % S; int g = gl / S;
  int b = g / 3, dir = g - (g / 3) * 3;
  float acc = cb[e];
#pragma unroll
  for (int k = 0; k < 4; ++k) {
    int ls = l + k - 3;
    if (ls >= 0) {
      int p = pos_from_l(dir, ls);
      acc = fmaf(cw[e * 4 + k], XZ[((size_t)b * S + p) * 384 + e], acc);
    }
  }
  float sg = 1.f / (1.f + __expf(-acc));
  xc[(size_t)gl * DI + e] = acc * sg;
}

// ---------------- K4: dt = softplus(dt_r @ Wdt^T + bdt) ------------------
__global__ __launch_bounds__(256) void k_dt(const float* __restrict__ xdbl,
    const float* __restrict__ Wdt, const float* __restrict__ bdt,
    float* __restrict__ dt) {
  int t = blockIdx.x * blockDim.x + threadIdx.x;
  if (t >= GG * S * DI) return;
  int e = t % DI; int gl = t / DI;
  const float* xr = xdbl + (size_t)gl * ND;
  float a = bdt[e];
#pragma unroll
  for (int r = 0; r < RK; ++r) a = fmaf(Wdt[e * RK + r], xr[r], a);
  float sp = (a > 20.f) ? a : log1pf(__expf(a));
  dt[(size_t)gl * DI + e] = sp;
}

// ---------------- K5A: per-chunk (prodA, end-state) ----------------------
__global__ __launch_bounds__(256) void k_scanA(const float* __restrict__ dt,
    const float* __restrict__ xc, const float* __restrict__ xdbl,
    const float* __restrict__ A_log, float* __restrict__ PA, float* __restrict__ EA) {
  int bid = blockIdx.x;
  int eb = bid % 12; int rest = bid / 12; int c = rest % NC; int g = rest / NC;
  int s = threadIdx.x & 15, el = threadIdx.x >> 4;
  int e = eb * 16 + el;
  float A_es = -__expf(A_log[e * NS + s]);
  float P = 1.f, E = 0.f;
  int l0 = c * LC;
#pragma unroll 4
  for (int l = l0; l < l0 + LC; ++l) {
    size_t row = (size_t)g * S + l;
    float dtv = dt[row * DI + e];
    float xcv = xc[row * DI + e];
    float Bm = xdbl[row * ND + RK + s];
    float dA = __expf(dtv * A_es);
    P *= dA;
    E = fmaf(dA, E, dtv * xcv * Bm);
  }
  int sidx = ((g * NC + c) * DI + e) * NS + s;
  PA[sidx] = P; EA[sidx] = E;
}

// ---------------- K5B: inter-chunk sequential combine --------------------
__global__ __launch_bounds__(256) void k_scanB(const float* __restrict__ PA,
    const float* __restrict__ EA, float* __restrict__ Hin) {
  int idx = blockIdx.x * blockDim.x + threadIdx.x;
  if (idx >= GG * DI * NS) return;
  int g = idx / (DI * NS); int es = idx - g * (DI * NS);
  float h = 0.f;
  for (int c = 0; c < NC; ++c) {
    int sidx = (g * NC + c) * DI * NS + es;
    Hin[sidx] = h;
    h = fmaf(PA[sidx], h, EA[sidx]);
  }
}

// ---------------- K5C: rescan + y = sum_s h*Cm, +Dp skip, *silu(z) -------
__global__ __launch_bounds__(256) void k_scanC(const float* __restrict__ dt,
    const float* __restrict__ xc, const float* __restrict__ xdbl,
    const float* __restrict__ Hin, const float* __restrict__ A_log,
    const float* __restrict__ Dp, const float* __restrict__ XZ,
    float* __restrict__ yg) {
  int bid = blockIdx.x;
  int eb = bid % 12; int rest = bid / 12; int c = rest % NC; int g = rest / NC;
  int b = g / 3, dir = g - (g / 3) * 3;
  int s = threadIdx.x & 15, el = threadIdx.x >> 4;
  int e = eb * 16 + el;
  float A_es = -__expf(A_log[e * NS + s]);
  int sidx = ((g * NC + c) * DI + e) * NS + s;
  float h = Hin[sidx];
  float dpe = Dp[e];
  int l0 = c * LC;
#pragma unroll 2
  for (int l = l0; l < l0 + LC; ++l) {
    size_t row = (size_t)g * S + l;
    float dtv = dt[row * DI + e];
    float xcv = xc[row * DI + e];
    float Bm = xdbl[row * ND + RK + s];
    float Cmv = xdbl[row * ND + RK + NS + s];
    float dA = __expf(dtv * A_es);
    h = fmaf(dA, h, dtv * xcv * Bm);
    float p = red16(h * Cmv);
    if (s == 0) {
      float v = fmaf(xcv, dpe, p);
      int pz = pos_from_l(dir, l);
      float zv = XZ[((size_t)b * S + pz) * 384 + DI + e];
      float gate = zv / (1.f + __expf(-zv));
      // identity scatter: output row is l (reference does NOT inverse-permute)
      yg[((size_t)b * S + l) * 576 + dir * DI + e] = v * gate;
    }
  }
}

// ---------------- fold Wout into proj_w: Mcat[o, dir*192+e] --------------
__global__ __launch_bounds__(256) void k_foldW(const float* __restrict__ proj_w,
    const float* __restrict__ Wout, float* __restrict__ Mcat) {
  int t = blockIdx.x * blockDim.x + threadIdx.x;
  if (t >= CC * 576) return;
  int o = t / 576; int j = t - o * 576; int dir = j / DI; int e = j - dir * DI;
  float a = 0.f;
  for (int c2 = 0; c2 < CC; ++c2)
    a = fmaf(proj_w[o * 288 + dir * CC + c2], Wout[c2 * DI + e], a);
  Mcat[t] = a;
}

extern "C" void kernel_launch(void* const* d_in, const int* in_sizes, int n_in,
                              void* d_out, int out_size, void* d_ws, size_t ws_size,
                              hipStream_t stream) {
  const float* x      = (const float*)d_in[0];
  const float* ln_w   = (const float*)d_in[1];
  const float* ln_b   = (const float*)d_in[2];
  const float* mln_w  = (const float*)d_in[3];
  const float* mln_b  = (const float*)d_in[4];
  const float* Win    = (const float*)d_in[5];
  const float* conv_w = (const float*)d_in[6];
  const float* conv_b = (const float*)d_in[7];
  const float* Wx     = (const float*)d_in[8];
  const float* Wdt    = (const float*)d_in[9];
  const float* bdt    = (const float*)d_in[10];
  const float* A_log  = (const float*)d_in[11];
  const float* Dp     = (const float*)d_in[12];
  const float* Wout   = (const float*)d_in[13];
  const float* proj_w = (const float*)d_in[14];
  const float* proj_b = (const float*)d_in[15];
  const float* fc1_w  = (const float*)d_in[16];
  const float* fc1_b  = (const float*)d_in[17];
  const float* fc2_w  = (const float*)d_in[18];
  const float* fc2_b  = (const float*)d_in[19];

  float* ws = (float*)d_ws;
  size_t off = 0;
  float* xn   = ws + off; off += (size_t)BB * S * CC;    // 1.536M
  float* XZ   = ws + off; off += (size_t)BB * S * 384;   // 6.144M
  float* xc   = ws + off; off += (size_t)GG * S * DI;    // 9.216M
  float* xdbl = ws + off; off += (size_t)GG * S * ND;    // 1.824M
  float* dt   = ws + off; off += (size_t)GG * S * DI;    // 9.216M
  float* PA   = ws + off; off += (size_t)GG * NC * DI * NS;
  float* EA   = ws + off; off += (size_t)GG * NC * DI * NS;
  float* Hin  = ws + off; off += (size_t)GG * NC * DI * NS;
  float* yg   = ws + off; off += (size_t)BB * S * 576;   // 9.216M
  float* Mcat = ws + off; off += (size_t)CC * 576;
  float* ores = ws + off; off += (size_t)BB * CC * S;    // 1.536M
  if (ws_size < off * sizeof(float)) return;             // ws too small -> clean fail
  float* h1   = XZ;   // XZ dead after k_scanC
  float* xln2 = xn;   // xn dead after first GEMM

  k_ln2<<<(BB * S + 255) / 256, 256, 0, stream>>>(x, ln_w, ln_b, mln_w, mln_b, xn);
  k_gemm<0, false, false, false><<<dim3(BB * S / 64, 384 / 64), 256, 0, stream>>>(
      xn, Win, nullptr, nullptr, XZ, BB * S, 384, CC);
  k_conv<<<(GG * S * DI + 255) / 256, 256, 0, stream>>>(XZ, conv_w, conv_b, xc);
  k_gemm<0, false, false, false><<<dim3(GG * S / 64, 1), 256, 0, stream>>>(
      xc, Wx, nullptr, nullptr, xdbl, GG * S, ND, DI);
  k_dt<<<(GG * S * DI + 255) / 256, 256, 0, stream>>>(xdbl, Wdt, bdt, dt);
  k_scanA<<<GG * NC * 12, 256, 0, stream>>>(dt, xc, xdbl, A_log, PA, EA);
  k_scanB<<<(GG * DI * NS + 255) / 256, 256, 0, stream>>>(PA, EA, Hin);
  k_scanC<<<GG * NC * 12, 256, 0, stream>>>(dt, xc, xdbl, Hin, A_log, Dp, XZ, yg);
  k_foldW<<<(CC * 576 + 255) / 256, 256, 0, stream>>>(proj_w, Wout, Mcat);
  k_gemm<0, true, true, true><<<dim3(BB * S / 64, 2), 256, 0, stream>>>(
      yg, Mcat, proj_b, x, ores, BB * S, CC, 576);
  k_ln1<<<(BB * S + 255) / 256, 256, 0, stream>>>(ores, ln_w, ln_b, xln2);
  k_gemm<1, true, false, false><<<dim3(BB * S / 64, 384 / 64), 256, 0, stream>>>(
      xln2, fc1_w, fc1_b, nullptr, h1, BB * S, 384, CC);
  k_gemm<0, true, true, true><<<dim3(BB * S / 64, 2), 256, 0, stream>>>(
      h1, fc2_w, fc2_b, ores, (float*)d_out, BB * S, CC, 384);
}